// Round 3
// baseline (129.258 us; speedup 1.0000x reference)
//
#include <hip/hip_runtime.h>

// Hapke BRDF — N=1M points, compute-bound (R1: VALUBusy 78%, HBM 17%).
// R3: 4 points/thread with float4-coalesced loads (3x float4 per vec3 array),
// polynomial acos, half-angle tan(phi/2) with explicit cphi==-1 pole (preserves
// ref's NaN->0 shadow path), and rcp consolidation (shared mu-denominator,
// fused B / tmp1 / PF reciprocals).

#define PIF  3.14159265358979323846f
#define EPSF 1e-5f

__device__ __forceinline__ float rcp(float x)  { return __builtin_amdgcn_rcpf(x); }
__device__ __forceinline__ float rsq(float x)  { return __builtin_amdgcn_rsqf(x); }
__device__ __forceinline__ float sqf(float x)  { return __builtin_amdgcn_sqrtf(x); }
__device__ __forceinline__ float nz(float y, float r) { return (y != y) ? r : y; }
__device__ __forceinline__ float clamp1(float x) { return fminf(fmaxf(x, -1.0f), 1.0f); }
// Abramowitz-Stegun 4.4.45 acos approx, |err| <= 6.7e-5 rad. phi only feeds
// phi/PI * E1 inside a denominator >= ~0.9 — error impact ~2e-5.
__device__ __forceinline__ float acos_poly(float x) {
    float a = fabsf(x);
    float r = sqf(1.0f - a) *
              (1.5707288f + a * (-0.2121144f + a * (0.0742610f + a * (-0.0187293f))));
    return (x >= 0.0f) ? r : (PIF - r);
}

// unpack 3 float4 (12 floats = 4 points x 3 comps) into per-point x/y/z
#define UNPACK3(P, X, Y, Z) do { \
    float4 _a = P[t3], _b = P[t3+1], _c = P[t3+2]; \
    X[0]=_a.x; Y[0]=_a.y; Z[0]=_a.z;  X[1]=_a.w; Y[1]=_b.x; Z[1]=_b.y; \
    X[2]=_b.z; Y[2]=_b.w; Z[2]=_c.x;  X[3]=_c.y; Y[3]=_c.z; Z[3]=_c.w; } while(0)
// unpack 3 float4 into flat [12] = index 3*p+k (point p, channel k)
#define UNPACK12(P, W) do { \
    float4 _a = P[t3], _b = P[t3+1], _c = P[t3+2]; \
    W[0]=_a.x; W[1]=_a.y; W[2]=_a.z; W[3]=_a.w; \
    W[4]=_b.x; W[5]=_b.y; W[6]=_b.z; W[7]=_b.w; \
    W[8]=_c.x; W[9]=_c.y; W[10]=_c.z; W[11]=_c.w; } while(0)

__global__ __launch_bounds__(256)
void hapke_kernel(const float4* __restrict__ l4, const float4* __restrict__ v4,
                  const float4* __restrict__ n4, const float4* __restrict__ w4,
                  const float4* __restrict__ b4, const float4* __restrict__ c4,
                  const float4* __restrict__ th4, const float4* __restrict__ h4,
                  const float4* __restrict__ B04, float4* __restrict__ out4, int N4)
{
    int t = blockIdx.x * blockDim.x + threadIdx.x;
    if (t >= N4) return;
    const int t3 = 3 * t;

    // ---- phase 1: geometry (frees l/v/n after) ----
    float ci[4], cv[4], cg[4], si[4], sv[4], cphi[4], phipi[4], ff[4], tg2[4];
    {
        float Lx[4], Ly[4], Lz[4], Vx[4], Vy[4], Vz[4], Nx[4], Ny[4], Nz[4];
        UNPACK3(l4, Lx, Ly, Lz);
        UNPACK3(v4, Vx, Vy, Vz);
        UNPACK3(n4, Nx, Ny, Nz);
        #pragma unroll
        for (int p = 0; p < 4; ++p) {
            ci[p] = clamp1(Nx[p]*Lx[p] + Ny[p]*Ly[p] + Nz[p]*Lz[p]);
            cv[p] = clamp1(Nx[p]*Vx[p] + Ny[p]*Vy[p] + Nz[p]*Vz[p]);
            cg[p] = clamp1(Lx[p]*Vx[p] + Ly[p]*Vy[p] + Lz[p]*Vz[p]);
            si[p] = sqf(1.0f - ci[p]*ci[p]);          // sin(acos x)
            sv[p] = sqf(1.0f - cv[p]*cv[p]);
            float cp = clamp1((cg[p] - ci[p]*cv[p]) * rcp(si[p]*sv[p] + 1e-8f));
            cphi[p]  = cp;
            phipi[p] = acos_poly(cp) * (1.0f / PIF);
            // ff = exp(-2 tan(phi/2)); half-angle identity. cphi==-1 is the ref's
            // tan overflow -> ff=inf -> NaN -> shad=0 path; preserve with inf.
            float u  = (1.0f - cp) * rcp(1.0f + cp);
            float fv = __expf(-2.0f * sqf(u));
            ff[p] = (cp <= -1.0f) ? __builtin_inff() : fv;
            tg2[p] = sqf((1.0f - cg[p]) * rcp(1.0f + cg[p]));   // tan(g/2)
        }
    }

    // ---- phase 2: roughness terms ----
    float ci_e[4], cv_e[4], shad[4], tmp1[4], logi[4], loge[4];
    {
        float4 thv = th4[t];
        float th[4] = {thv.x, thv.y, thv.z, thv.w};
        #pragma unroll
        for (int p = 0; p < 4; ++p) {
            float s = __sinf(th[p] + EPSF), cth = __cosf(th[p] + EPSF);
            float tt     = s * rcp(cth);              // tan(th+EPS); also used for tan(th): diff <= 2e-5
            float cot_th = cth * rcp(s);
            float cot_i = ci[p] * rcp(si[p]);         // si=0 -> inf -> E*=0 (ref limit)
            float cot_e = cv[p] * rcp(sv[p]);
            float E1i = nz(__expf(-(2.0f/PIF) * cot_th * cot_i), 0.0f);
            float E1e = nz(__expf(-(2.0f/PIF) * cot_th * cot_e), 0.0f);
            float ct2 = cot_th * cot_th;
            float E2i = nz(__expf(-(1.0f/PIF) * ct2 * cot_i*cot_i), 0.0f);
            float E2e = nz(__expf(-(1.0f/PIF) * ct2 * cot_e*cot_e), 0.0f);
            float chit = rsq(1.0f + PIF * tt * tt);
            float etai = nz(chit * (ci[p] + si[p]*tt * (E2i * rcp(2.0f - E1i))), 0.0f);
            float etae = nz(chit * (cv[p] + sv[p]*tt * (E2e * rcp(2.0f - E1e))), 0.0f);

            float sp2 = 0.5f * (1.0f - cphi[p]);      // sin^2(phi/2)
            bool ile = (ci[p] >= cv[p]);              // sza <= vza
            float Ea  = ile ? E1e : E1i;              // shared denominator: select then 1 rcp
            float Eb  = ile ? E1i : E1e;
            float rd  = rcp(2.0f - Ea - phipi[p]*Eb);
            float ymu  = (ile ? (E2e - sp2*E2i)         : (cphi[p]*E2i + sp2*E2e)) * rd;
            float ymu0 = (ile ? (cphi[p]*E2e + sp2*E2i) : (E2i - sp2*E2e)) * rd;
            cv_e[p] = nz(chit * (cv[p] + sv[p]*tt*ymu ), cv[p]);   // _mu_eff
            ci_e[p] = nz(chit * (ci[p] + si[p]*tt*ymu0), ci[p]);   // _mu0_eff

            float r_etai = rcp(etai), r_etae = rcp(etae);
            float ci_etai = ci[p] * r_etai, cv_etae = cv[p] * r_etae;
            float temp = cv_e[p] * r_etae * ci_etai * chit;
            float den = 1.0f - ff[p] + ff[p]*chit*(ile ? ci_etai : cv_etae);
            shad[p] = nz(temp * rcp(den), 0.0f);      // ff=inf -> den=NaN -> 0 (matches ref)

            tmp1[p] = ci_e[p] * rcp((ci_e[p] + cv_e[p]) * ci[p]);
            logi[p] = __logf(fabsf((1.0f + ci_e[p]) * rcp(ci_e[p])));
            loge[p] = __logf(fabsf((1.0f + cv_e[p]) * rcp(cv_e[p])));
        }
    }

    // ---- phase 3: per-channel PF/HF + output ----
    float W[12], Bb[12], Cc[12], o[12], Bv[4];
    UNPACK12(w4, W);
    UNPACK12(b4, Bb);
    UNPACK12(c4, Cc);
    {
        float4 hv = h4[t], B0v = B04[t];
        float hh[4] = {hv.x, hv.y, hv.z, hv.w};
        float bb[4] = {B0v.x, B0v.y, B0v.z, B0v.w};
        #pragma unroll
        for (int p = 0; p < 4; ++p)   // B0/(1 + tan(g/2)/h) + 1 = B0*h/(h+tg2) + 1
            Bv[p] = bb[p] * hh[p] * rcp(hh[p] + tg2[p]) + 1.0f;
    }
    #pragma unroll
    for (int p = 0; p < 4; ++p) {
        #pragma unroll
        for (int k = 0; k < 3; ++k) {
            int j = 3*p + k;
            float wk = W[j], bk = Bb[j], ck = Cc[j];
            float b2 = bk * bk, bx = bk * cg[p];
            float t1 = 1.0f - 2.0f*bx + b2;           // >= (1-0.8)^2 = 0.04 > 0
            float t2 = 1.0f + 2.0f*bx + b2;
            float q1 = t1 * sqf(t1) + 1e-6f;
            float q2 = t2 * sqf(t2) + 1e-6f;
            float P = (1.0f - b2) * (ck*q2 + (1.0f - ck)*q1) * rcp(q1*q2);
            float gamma = sqf(1.0f - wk);
            float ro = (1.0f - gamma) * rcp(1.0f + gamma);
            float Hi = nz(rcp(1.0f - wk*ci_e[p]*(ro + (1.0f - 2.0f*ro*ci_e[p])*0.5f*logi[p])), 1.0f);
            float Hv = nz(rcp(1.0f - wk*cv_e[p]*(ro + (1.0f - 2.0f*ro*cv_e[p])*0.5f*loge[p])), 1.0f);
            float tmp2 = P * Bv[p] + Hi * Hv - 1.0f;
            o[j] = wk * 0.25f * tmp1[p] * tmp2 * shad[p];   // w / HPK_SCL
        }
    }
    out4[t3]   = make_float4(o[0], o[1], o[2],  o[3]);
    out4[t3+1] = make_float4(o[4], o[5], o[6],  o[7]);
    out4[t3+2] = make_float4(o[8], o[9], o[10], o[11]);
}

extern "C" void kernel_launch(void* const* d_in, const int* in_sizes, int n_in,
                              void* d_out, int out_size, void* d_ws, size_t ws_size,
                              hipStream_t stream) {
    const float4* l4  = (const float4*)d_in[0];
    const float4* v4  = (const float4*)d_in[1];
    const float4* n4  = (const float4*)d_in[2];
    const float4* w4  = (const float4*)d_in[3];
    const float4* b4  = (const float4*)d_in[4];
    const float4* c4  = (const float4*)d_in[5];
    const float4* th4 = (const float4*)d_in[6];
    const float4* h4  = (const float4*)d_in[7];
    const float4* B04 = (const float4*)d_in[8];
    float4* out4 = (float4*)d_out;

    int N  = in_sizes[6];          // theta is (N,); N = 1048576, divisible by 4
    int N4 = N >> 2;               // 4 points per thread
    const int block = 256;
    int grid = (N4 + block - 1) / block;
    hapke_kernel<<<grid, block, 0, stream>>>(l4, v4, n4, w4, b4, c4,
                                             th4, h4, B04, out4, N4);
}

// Round 4
// 123.862 us; speedup vs baseline: 1.0436x; 1.0436x over previous
//
#include <hip/hip_runtime.h>

// Hapke BRDF — elementwise, N=1M, VALU-bound.
// R4 = R2 structure (1 point/thread, VGPR ~24, high occupancy) + R3's scalar
// math wins: polynomial acos, half-angle ff with explicit cphi=-1 pole,
// select-before-rcp mu-denominator, fused B / tmp1 / PF reciprocals.
// R3's 4-pt/thread batching regressed (26 -> ~31 us: register pressure) — reverted.

#define PIF  3.14159265358979323846f
#define EPSF 1e-5f

__device__ __forceinline__ float rcp(float x)  { return __builtin_amdgcn_rcpf(x); }
__device__ __forceinline__ float rsq(float x)  { return __builtin_amdgcn_rsqf(x); }
__device__ __forceinline__ float sqf(float x)  { return __builtin_amdgcn_sqrtf(x); }
__device__ __forceinline__ float nz(float y, float r) { return (y != y) ? r : y; }
__device__ __forceinline__ float clamp1(float x) { return fminf(fmaxf(x, -1.0f), 1.0f); }
// Abramowitz-Stegun 4.4.45: |err| <= 6.7e-5 rad. phi only feeds phi/PI * E1
// inside a denominator >= ~0.9 — error impact ~2e-5, far under threshold slack.
__device__ __forceinline__ float acos_poly(float x) {
    float a = fabsf(x);
    float r = sqf(1.0f - a) *
              (1.5707288f + a * (-0.2121144f + a * (0.0742610f + a * (-0.0187293f))));
    return (x >= 0.0f) ? r : (PIF - r);
}

__global__ __launch_bounds__(256)
void hapke_kernel(const float* __restrict__ pts2l, const float* __restrict__ pts2c,
                  const float* __restrict__ normal, const float* __restrict__ w,
                  const float* __restrict__ b, const float* __restrict__ c,
                  const float* __restrict__ theta, const float* __restrict__ h,
                  const float* __restrict__ B0, float* __restrict__ out, int N)
{
    int idx = blockIdx.x * blockDim.x + threadIdx.x;
    if (idx >= N) return;
    const int i3 = idx * 3;

    float lx = pts2l[i3], ly = pts2l[i3+1], lz = pts2l[i3+2];
    float vx = pts2c[i3], vy = pts2c[i3+1], vz = pts2c[i3+2];
    float nx = normal[i3], ny = normal[i3+1], nzc = normal[i3+2];

    // ci, cv in [0,1] (l,v flipped into normal's hemisphere by setup)
    float ci = clamp1(nx*lx + ny*ly + nzc*lz);
    float cv = clamp1(nx*vx + ny*vy + nzc*vz);
    float cg = clamp1(lx*vx + ly*vy + lz*vz);
    float si = sqf(1.0f - ci*ci);            // sin(acos x) — exact
    float sv = sqf(1.0f - cv*cv);
    float cphi = clamp1((cg - ci*cv) * rcp(si*sv + 1e-8f));
    float phipi = acos_poly(cphi) * (1.0f / PIF);

    // ff = exp(-2 tan((phi+EPS)/2)) via half-angle; cphi==-1 is the ref's tan
    // overflow -> ff=inf -> NaN -> shad=0 path, preserved explicitly.
    float ffu = (1.0f - cphi) * rcp(1.0f + cphi);
    float ff  = (cphi <= -1.0f) ? __builtin_inff() : __expf(-2.0f * sqf(ffu));

    float th = theta[idx];
    float s = __sinf(th + EPSF), cth = __cosf(th + EPSF);
    float tt     = s * rcp(cth);             // tan(th+EPS); reused for tan(th), diff <= 2e-5
    float cot_th = cth * rcp(s);
    float cot_i  = ci * rcp(si);             // si=0 -> inf -> E*=0 (ref limit)
    float cot_e  = cv * rcp(sv);

    float E1i = nz(__expf(-(2.0f/PIF) * cot_th * cot_i), 0.0f);
    float E1e = nz(__expf(-(2.0f/PIF) * cot_th * cot_e), 0.0f);
    float ct2 = cot_th * cot_th;
    float E2i = nz(__expf(-(1.0f/PIF) * ct2 * cot_i*cot_i), 0.0f);
    float E2e = nz(__expf(-(1.0f/PIF) * ct2 * cot_e*cot_e), 0.0f);

    float chit = rsq(1.0f + PIF * tt * tt);
    float etai = nz(chit * (ci + si * tt * (E2i * rcp(2.0f - E1i))), 0.0f);
    float etae = nz(chit * (cv + sv * tt * (E2e * rcp(2.0f - E1e))), 0.0f);

    float sp2 = 0.5f * (1.0f - cphi);        // sin^2(phi/2) — exact half-angle
    bool  ile = (ci >= cv);                  // sza <= vza (branches continuous at tie)
    float Ea  = ile ? E1e : E1i;             // shared denominator: select, then ONE rcp
    float Eb  = ile ? E1i : E1e;
    float rd  = rcp(2.0f - Ea - phipi * Eb);
    float ymu  = (ile ? (E2e - sp2*E2i)       : (cphi*E2i + sp2*E2e)) * rd;
    float ymu0 = (ile ? (cphi*E2e + sp2*E2i)  : (E2i - sp2*E2e)) * rd;
    float cv_e = nz(chit * (cv + sv * tt * ymu ), cv);    // _mu_eff
    float ci_e = nz(chit * (ci + si * tt * ymu0), ci);    // _mu0_eff

    // _S (shadowing)
    float r_etai = rcp(etai), r_etae = rcp(etae);
    float ci_etai = ci * r_etai, cv_etae = cv * r_etae;
    float temp = cv_e * r_etae * ci_etai * chit;
    float den  = 1.0f - ff + ff * chit * (ile ? ci_etai : cv_etae);
    float shad = nz(temp * rcp(den), 0.0f);  // ff=inf -> den=NaN -> 0 (matches ref)

    // B0/(1 + tan(g/2)/h) + 1 = B0*h/(h + tg2) + 1; tan(g/2)=sqrt((1-cg)/(1+cg))
    float tg2 = sqf((1.0f - cg) * rcp(1.0f + cg));
    float hh  = h[idx];
    float B   = B0[idx] * hh * rcp(hh + tg2) + 1.0f;
    float tmp1 = ci_e * rcp((ci_e + cv_e) * ci);

    float logi = 0.5f * __logf(fabsf((1.0f + ci_e) * rcp(ci_e)));
    float loge = 0.5f * __logf(fabsf((1.0f + cv_e) * rcp(cv_e)));

    #pragma unroll
    for (int k = 0; k < 3; ++k) {
        float wk = w[i3+k], bk = b[i3+k], ck = c[i3+k];
        float b2 = bk * bk, bx = bk * cg;
        float t1 = 1.0f - 2.0f*bx + b2;      // >= (1-0.8)^2 = 0.04 > 0
        float t2 = 1.0f + 2.0f*bx + b2;
        float q1 = t1 * sqf(t1) + 1e-6f;
        float q2 = t2 * sqf(t2) + 1e-6f;
        float P  = (1.0f - b2) * (ck*q2 + (1.0f - ck)*q1) * rcp(q1*q2);
        float gamma = sqf(1.0f - wk);
        float ro = (1.0f - gamma) * rcp(1.0f + gamma);
        float Hi = nz(rcp(1.0f - wk*ci_e*(ro + (1.0f - 2.0f*ro*ci_e)*logi)), 1.0f);
        float Hv = nz(rcp(1.0f - wk*cv_e*(ro + (1.0f - 2.0f*ro*cv_e)*loge)), 1.0f);
        float tmp2 = P * B + Hi * Hv - 1.0f;
        out[i3+k] = wk * 0.25f * tmp1 * tmp2 * shad;   // w / HPK_SCL
    }
}

extern "C" void kernel_launch(void* const* d_in, const int* in_sizes, int n_in,
                              void* d_out, int out_size, void* d_ws, size_t ws_size,
                              hipStream_t stream) {
    const float* pts2l  = (const float*)d_in[0];
    const float* pts2c  = (const float*)d_in[1];
    const float* normal = (const float*)d_in[2];
    const float* w      = (const float*)d_in[3];
    const float* b      = (const float*)d_in[4];
    const float* c      = (const float*)d_in[5];
    const float* theta  = (const float*)d_in[6];
    const float* h      = (const float*)d_in[7];
    const float* B0     = (const float*)d_in[8];
    float* out = (float*)d_out;

    int N = in_sizes[6];
    const int block = 256;
    int grid = (N + block - 1) / block;
    hapke_kernel<<<grid, block, 0, stream>>>(pts2l, pts2c, normal, w, b, c,
                                             theta, h, B0, out, N);
}